// Round 8
// baseline (112.960 us; speedup 1.0000x reference)
//
#include <hip/hip_runtime.h>
#include <math.h>

// PLIF (parametric LIF) forward, heterogeneous per-feature decay/threshold.
// x: [B=4, N=1024, T=128, D=128] fp32, sequential scan over T per (b,n,d):
//   v = v * sigmoid(decay[d]) + x[t]
//   s = (v > sigmoid(v_th[d]) + 0.1) ? 1 : 0
//   v = s ? 0 : v        (hard reset; exact since s in {0,1})
//
// R8: barrier-free wave-private staging. R6 (94.4us, 90.5% of copy ceiling)
//     pays 32 block-wide barriers, each preceded by a compiler-emitted
//     s_waitcnt vmcnt(0) drain; R7 showed amortizing them doesn't work.
//     Here each WAVE owns one row: stage chunk with float4 (1024B contiguous
//     per wave-instr, the pattern that won R6), compute 2 feature-chains per
//     lane from wave-private LDS (b64, minimum-aliasing), write spikes back
//     in place, store out as float4. Producer == consumer == same wave ->
//     NO __syncthreads anywhere; ordering via per-wave lgkmcnt only; waves
//     free-run and self-stagger. Trade: 16 waves/CU (vs R6's 32) -- R3->R5
//     showed weak occupancy sensitivity; in-flight bytes stay ample.
//
// __fmul_rn/__fadd_rn prevent fma contraction so fp32 rounding matches the
// mul-then-add numpy reference exactly (spike compares are boundary-
// sensitive: one ulp flip -> absmax 1.0). R1/R3-R7 passed absmax 0.0.

#define T_STEPS 128
#define D_FEAT  128
#define CT      8                 // time-steps per staged chunk
#define CTD     (CT * D_FEAT)     // 1024 floats per wave-chunk (4 KB)
#define NCHUNK  (T_STEPS / CT)    // 16 chunks

typedef float f32x2 __attribute__((ext_vector_type(2)));
typedef float f32x4 __attribute__((ext_vector_type(4)));

__global__ __launch_bounds__(256)
void plif_fwd_kernel(const f32x4* __restrict__ x4,
                     const float* __restrict__ decay,
                     const float* __restrict__ vth,
                     f32x4* __restrict__ out4)
{
    __shared__ float xs[4][CTD];            // 16 KB: 4 KB private per wave

    const int tid = threadIdx.x;
    const int w   = tid >> 6;               // wave index in block
    const int l   = tid & 63;               // lane
    const int row = blockIdx.x * 4 + w;     // one row per wave
    const int d0  = l * 2;                  // this lane's 2 features

    // per-feature constants (4 expf per thread -- negligible)
    const float decA = 1.0f / (1.0f + expf(-decay[d0 + 0]));
    const float decB = 1.0f / (1.0f + expf(-decay[d0 + 1]));
    const float thA  = 1.0f / (1.0f + expf(-vth[d0 + 0])) + 0.1f;
    const float thB  = 1.0f / (1.0f + expf(-vth[d0 + 1])) + 0.1f;

    const size_t rowq = (size_t)T_STEPS * D_FEAT / 4;   // float4s per row
    const f32x4* __restrict__ xr  = x4  + (size_t)row * rowq;
    f32x4* __restrict__       orw = out4 + (size_t)row * rowq;

    float* __restrict__ mylds = xs[w];

    float vA = 0.0f, vB = 0.0f;

    for (int c = 0; c < NCHUNK; ++c) {
        const size_t cq = (size_t)c * (CTD / 4);        // float4 offset in row

        // ---- stage: 4 float4 loads/lane; each wave-instr is 1024B contiguous
#pragma unroll
        for (int p = 0; p < 4; ++p) {
            const f32x4 tmp = __builtin_nontemporal_load(xr + cq + p * 64 + l);
            *(f32x4*)&mylds[(p * 64 + l) * 4] = tmp;
        }

        // ---- compute CT steps of this lane's 2 chains (wave-private LDS,
        //      in-place spike write-back; ordering via per-wave lgkmcnt) ----
#pragma unroll
        for (int i = 0; i < CT; ++i) {
            const f32x2 xv = *(const f32x2*)&mylds[i * D_FEAT + d0];

            vA = __fadd_rn(__fmul_rn(vA, decA), xv.x);
            const bool fA = (vA > thA);
            const float sA = fA ? 1.0f : 0.0f;
            vA = fA ? 0.0f : vA;

            vB = __fadd_rn(__fmul_rn(vB, decB), xv.y);
            const bool fB = (vB > thB);
            const float sB = fB ? 1.0f : 0.0f;
            vB = fB ? 0.0f : vB;

            f32x2 sv; sv.x = sA; sv.y = sB;
            *(f32x2*)&mylds[i * D_FEAT + d0] = sv;
        }

        // ---- store: 4 float4 stores/lane, 1024B contiguous per wave-instr
#pragma unroll
        for (int p = 0; p < 4; ++p) {
            const f32x4 sv = *(const f32x4*)&mylds[(p * 64 + l) * 4];
            __builtin_nontemporal_store(sv, orw + cq + p * 64 + l);
        }
    }
}

extern "C" void kernel_launch(void* const* d_in, const int* in_sizes, int n_in,
                              void* d_out, int out_size, void* d_ws, size_t ws_size,
                              hipStream_t stream)
{
    const float* x     = (const float*)d_in[0];
    const float* decay = (const float*)d_in[1];
    const float* vth   = (const float*)d_in[2];
    float*       out   = (float*)d_out;

    const int total  = in_sizes[0];                    // B*N*T*D = 67108864
    const int rows   = total / (T_STEPS * D_FEAT);     // B*N = 4096
    const int blocks = rows / 4;                       // 1024 (4 waves/block)
    const int block  = 256;

    plif_fwd_kernel<<<blocks, block, 0, stream>>>(
        (const f32x4*)x, decay, vth, (f32x4*)out);
}

// Round 9
// 93.216 us; speedup vs baseline: 1.2118x; 1.2118x over previous
//
#include <hip/hip_runtime.h>
#include <math.h>

// PLIF (parametric LIF) forward, heterogeneous per-feature decay/threshold.
// x: [B=4, N=1024, T=128, D=128] fp32, sequential scan over T per (b,n,d):
//   v = v * sigmoid(decay[d]) + x[t]
//   s = (v > sigmoid(v_th[d]) + 0.1) ? 1 : 0
//   v = s ? 0 : v        (hard reset; exact since s in {0,1})
//
// R9: R6 (94.4us = 90.5% of copy ceiling; LDS-staged wide I/O, 2 rows/block,
//     32 waves/CU) with RAW barriers. hipcc's __syncthreads emits
//     s_waitcnt vmcnt(0) before s_barrier, gang-stalling every block on the
//     retirement of the previous chunk's 16KB of NT spike-stores, 16x per
//     block (R8 showed removing barriers ENTIRELY loses to occupancy/
//     serialization; this keeps the R6 structure and removes only the
//     vmem drain). Correctness needs only lgkmcnt(0): cross-thread exchange
//     is purely through LDS (xs: stage->compute, ss: compute->store), each
//     fenced by one raw barrier; sched_barrier(0) + "memory" clobber pin
//     LDS ops on the correct side (guide rule #18); global stores are
//     disjoint, write-once, never re-read.
//
// __fmul_rn/__fadd_rn prevent fma contraction so fp32 rounding matches the
// mul-then-add numpy reference exactly (spike compares are boundary-
// sensitive: one ulp flip -> absmax 1.0). R1/R3-R8 passed absmax 0.0.

#define T_STEPS 128
#define D_FEAT  128
#define CT      8                 // time-steps per staged chunk
#define CTD     (CT * D_FEAT)     // 1024 floats per row-chunk
#define NCHUNK  (T_STEPS / CT)    // 16 chunks

typedef float f32x4 __attribute__((ext_vector_type(4)));

// Workgroup barrier WITHOUT the vmcnt(0) drain __syncthreads would emit:
// orders LDS ops only, leaves global (NT store) traffic in flight.
__device__ __forceinline__ void barrier_lds_only()
{
    __builtin_amdgcn_sched_barrier(0);
    asm volatile("s_waitcnt lgkmcnt(0)" ::: "memory");
    __builtin_amdgcn_s_barrier();
    __builtin_amdgcn_sched_barrier(0);
}

__global__ __launch_bounds__(256)
void plif_fwd_kernel(const f32x4* __restrict__ x4,
                     const float* __restrict__ decay,
                     const float* __restrict__ vth,
                     f32x4* __restrict__ out4)
{
    __shared__ float xs[2 * CTD];   // 8 KB: [2 rows][CT][D]
    __shared__ float ss[2 * CTD];   // 8 KB spikes

    const int tid  = threadIdx.x;
    const int lrow = tid >> 7;              // 0/1: which of the block's rows
    const int d    = tid & (D_FEAT - 1);    // feature index
    const int r0   = blockIdx.x * 2;        // first row of this block

    // per-feature constants (2 expf per thread -- negligible)
    const float dec = 1.0f / (1.0f + expf(-decay[d]));
    const float th  = 1.0f / (1.0f + expf(-vth[d])) + 0.1f;

    const size_t rowq = (size_t)T_STEPS * D_FEAT / 4;   // float4s per row

    float v = 0.0f;

    for (int c = 0; c < NCHUNK; ++c) {
        const size_t cq = (size_t)(c * CT) * D_FEAT / 4; // chunk offset (float4)

        // ---- stage x: 2 rounds of fully-contiguous 4KB float4 loads ----
#pragma unroll
        for (int p = 0; p < 2; ++p) {
            const f32x4 tmp = __builtin_nontemporal_load(
                x4 + (size_t)(r0 + p) * rowq + cq + (size_t)tid);
            *(f32x4*)&xs[p * CTD + tid * 4] = tmp;
        }
        barrier_lds_only();   // xs visible; prior chunk's stores stay in flight

        // ---- compute CT steps of this thread's (row, d) chain ----
#pragma unroll
        for (int i = 0; i < CT; ++i) {
            const float xv = xs[lrow * CTD + i * D_FEAT + d];
            v = __fadd_rn(__fmul_rn(v, dec), xv);
            const bool f = (v > th);
            ss[lrow * CTD + i * D_FEAT + d] = f ? 1.0f : 0.0f;
            v = f ? 0.0f : v;
        }
        barrier_lds_only();   // ss visible

        // ---- store spikes: 2 rounds of contiguous float4 stores ----
        // (no trailing barrier: next stage overwrites xs, which no wave
        //  reads after the compute barrier; each wave's ss reads drain at
        //  the next barrier's lgkmcnt(0) before ss is rewritten)
#pragma unroll
        for (int p = 0; p < 2; ++p) {
            const f32x4 sv = *(const f32x4*)&ss[p * CTD + tid * 4];
            __builtin_nontemporal_store(sv,
                out4 + (size_t)(r0 + p) * rowq + cq + (size_t)tid);
        }
    }
}

extern "C" void kernel_launch(void* const* d_in, const int* in_sizes, int n_in,
                              void* d_out, int out_size, void* d_ws, size_t ws_size,
                              hipStream_t stream)
{
    const float* x     = (const float*)d_in[0];
    const float* decay = (const float*)d_in[1];
    const float* vth   = (const float*)d_in[2];
    float*       out   = (float*)d_out;

    const int total  = in_sizes[0];                    // B*N*T*D = 67108864
    const int rows   = total / (T_STEPS * D_FEAT);     // B*N = 4096
    const int blocks = rows / 2;                       // 2048
    const int block  = 256;

    plif_fwd_kernel<<<blocks, block, 0, stream>>>(
        (const f32x4*)x, decay, vth, (f32x4*)out);
}